// Round 3
// baseline (587.657 us; speedup 1.0000x reference)
//
#include <hip/hip_runtime.h>
#include <stdint.h>

#define CDIM   4096
#define S_N    3355443
#define R_N    1048576
#define N1     (S_N + R_N)                 // 4404019 contributions
#define TILE   4096
#define NTILES ((N1 + TILE - 1) / TILE)    // 1076
#define NPAD   (NTILES * TILE)             // 4407296
#define NSB    (NPAD / 256)                // 17216
#define PAD_KEY 0xFFFFFFu
#define PAD_VAL 0xFFFFFFFFu                // impossible value bits (sums are >= +0)
#define VALMASK 0x07FFFFFFu                // status: [31:29]=epoch [28:27]=flag [26:0]=count

static __device__ __forceinline__ unsigned ld_st(unsigned* p){
  return __hip_atomic_load(p, __ATOMIC_RELAXED, __HIP_MEMORY_SCOPE_AGENT);
}
static __device__ __forceinline__ void st_st(unsigned* p, unsigned v){
  __hip_atomic_store(p, v, __ATOMIC_RELAXED, __HIP_MEMORY_SCOPE_AGENT);
}

// Exclusive block-wide scan over 256 threads (4 waves). Contains syncthreads.
static __device__ __forceinline__ unsigned blockScanExcl(unsigned v, unsigned t,
                                                         unsigned* lw, unsigned* tot){
  unsigned lane = t & 63u, w = t >> 6;
  unsigned x = v;
  #pragma unroll
  for (int off = 1; off < 64; off <<= 1){
    unsigned y = __shfl_up(x, off, 64);
    if (lane >= (unsigned)off) x += y;
  }
  if (lane == 63u) lw[w] = x;
  __syncthreads();
  unsigned woff = 0;
  for (unsigned i = 0; i < w; i++) woff += lw[i];
  *tot = lw[0] + lw[1] + lw[2] + lw[3];
  __syncthreads();
  return x + woff - v;
}

// Zero status array + global digit totals + tickets (ws is poisoned 0xAA each launch).
__global__ __launch_bounds__(256) void k_zero(unsigned* __restrict__ p, unsigned n){
  unsigned i = blockIdx.x * 256u + threadIdx.x;
  if (i < n) p[i] = 0u;
}

// Build packed contributions (high32 = key, low32 = value bits) AND the three
// global key-digit histograms in one pass (digit totals are permutation-
// invariant, so per-pass re-histogramming is unnecessary).
__global__ __launch_bounds__(256) void k_build_h3(const int* __restrict__ sidx,
                                                  const int* __restrict__ ridx,
                                                  const float* __restrict__ rval,
                                                  const float* __restrict__ grad,
                                                  uint64_t* __restrict__ A,
                                                  unsigned* __restrict__ dtotAll){
  __shared__ unsigned h[3*256];
  unsigned t = threadIdx.x;
  h[t] = 0; h[256+t] = 0; h[512+t] = 0;
  __syncthreads();
  unsigned base = blockIdx.x * (unsigned)TILE;
  #pragma unroll
  for (int r = 0; r < 16; r++){
    unsigned i = base + (unsigned)r*256u + t;
    uint32_t key, vb;
    if (i < S_N){
      key = (uint32_t)sidx[i];
      vb  = __float_as_uint(fabsf(grad[i]));
    } else if (i < N1){
      unsigned j = i - S_N;
      key = (uint32_t)(ridx[2u*j] * CDIM + ridx[2u*j + 1u]);
      const float ADJF = (float)(1.0 - (3355443.0 / 16777216.0) * (1.0 - 0.95));
      vb = __float_as_uint(ADJF * rval[j]);
    } else {
      key = PAD_KEY; vb = PAD_VAL;
    }
    A[i] = ((uint64_t)key << 32) | (uint64_t)vb;
    atomicAdd(&h[key & 0xFFu], 1u);
    atomicAdd(&h[256u + ((key >> 8) & 0xFFu)], 1u);
    atomicAdd(&h[512u + ((key >> 16) & 0xFFu)], 1u);
  }
  __syncthreads();
  if (h[t])     atomicAdd(&dtotAll[t],        h[t]);
  if (h[256+t]) atomicAdd(&dtotAll[256u + t], h[256+t]);
  if (h[512+t]) atomicAdd(&dtotAll[512u + t], h[512+t]);
}

// Global histograms of all four value-sort digits in one pass over candidates.
__global__ __launch_bounds__(256) void k_ghist4(const uint64_t* __restrict__ A,
                                                unsigned* __restrict__ dtotAll){
  __shared__ unsigned h[4*256];
  unsigned t = threadIdx.x;
  h[t] = 0; h[256+t] = 0; h[512+t] = 0; h[768+t] = 0;
  __syncthreads();
  size_t base = (size_t)blockIdx.x * TILE;
  #pragma unroll
  for (int r = 0; r < 16; r++){
    uint32_t x = (uint32_t)A[base + (size_t)r*256 + t];
    atomicAdd(&h[x & 0xFFu], 1u);
    atomicAdd(&h[256u + ((x >> 8)  & 0xFFu)], 1u);
    atomicAdd(&h[512u + ((x >> 16) & 0xFFu)], 1u);
    atomicAdd(&h[768u + (x >> 24)], 1u);
  }
  __syncthreads();
  #pragma unroll
  for (int rr = 0; rr < 4; rr++){
    unsigned v = h[rr*256 + t];
    if (v) atomicAdd(&dtotAll[(3u + rr)*256u + t], v);
  }
}

// ---- Onesweep stable radix scatter ---------------------------------------
// Ticket-ordered tiles + decoupled lookback replace per-pass hist/scanrows.
// Phase A: per-wave stable ballot ranks. Phase B: publish AGG counts, block
// digit scans, lookback for global tile prefix, publish INC. Phase C/D: LDS
// reorder + coalesced sweep to global (or fused output emission on FINAL).
template <bool FINAL>
__device__ __forceinline__ void scatter_os(const uint64_t* __restrict__ in,
                                           uint64_t* __restrict__ out,
                                           float* __restrict__ fout,
                                           unsigned shift, unsigned epoch,
                                           unsigned* __restrict__ status,
                                           const unsigned* __restrict__ drow,
                                           unsigned* __restrict__ ticket){
  __shared__ unsigned wrun[4*256];
  __shared__ unsigned gput[256];
  __shared__ unsigned lw[4];
  __shared__ unsigned vts;
  __shared__ uint64_t stage[TILE];       // 32 KB
  unsigned t = threadIdx.x, lane = t & 63u, w = t >> 6;
  if (t == 0) vts = atomicAdd(ticket, 1u);
  wrun[t] = 0; wrun[256+t] = 0; wrun[512+t] = 0; wrun[768+t] = 0;
  __syncthreads();
  unsigned vt = vts;
  uint64_t ltm = (lane == 0) ? 0ull : (~0ull >> (64u - lane));
  uint64_t elems[16]; unsigned rnk[16]; unsigned dg[16];
  size_t base = (size_t)vt * TILE + (size_t)w * 1024;
  #pragma unroll
  for (int r = 0; r < 16; r++){
    uint64_t e = in[base + (size_t)r*64 + lane];
    elems[r] = e;
    unsigned d = (unsigned)((e >> shift) & 0xFF);
    uint64_t m = ~0ull;
    #pragma unroll
    for (int b = 0; b < 8; b++){
      uint64_t bb = __ballot((d >> b) & 1u);
      m &= ((d >> b) & 1u) ? bb : ~bb;
    }
    unsigned rr   = (unsigned)__popcll(m & ltm);
    unsigned prev = wrun[w*256 + d];
    __builtin_amdgcn_wave_barrier();
    if (rr == 0) wrun[w*256 + d] = prev + (unsigned)__popcll(m);
    __builtin_amdgcn_wave_barrier();
    rnk[r] = prev + rr;
    dg[r]  = d;
  }
  __syncthreads();
  unsigned d = t;
  unsigned c0 = wrun[d], c1 = wrun[256+d], c2 = wrun[512+d], c3 = wrun[768+d];
  unsigned cnt = c0 + c1 + c2 + c3;
  // Publish aggregate immediately (tile 0 publishes inclusive directly).
  if (vt == 0) st_st(&status[d],            (epoch << 29) | (2u << 27) | cnt);
  else         st_st(&status[vt*256u + d],  (epoch << 29) | (1u << 27) | cnt);
  unsigned tot, tot2;
  unsigned ldig  = blockScanExcl(cnt, t, lw, &tot);       // local digit start
  unsigned dbase = blockScanExcl(drow[d], t, lw, &tot2);  // global digit base
  // Decoupled lookback: sum predecessor AGGs until an INC short-circuits.
  unsigned excl = 0;
  if (vt){
    int j = (int)vt - 1;
    unsigned running = 0;
    bool fin = false;
    while (!fin){
      int nb = (j >= 3) ? 4 : (j + 1);
      unsigned wv[4];
      #pragma unroll
      for (int b = 0; b < 4; b++)
        if (b < nb) wv[b] = ld_st(&status[(unsigned)(j - b)*256u + d]);
      #pragma unroll
      for (int b = 0; b < 4; b++){
        if (b < nb && !fin){
          unsigned x = wv[b];
          while ((x >> 29) != epoch || !((x >> 27) & 3u))
            x = ld_st(&status[(unsigned)(j - b)*256u + d]);
          running += x & VALMASK;
          if (((x >> 27) & 3u) == 2u) fin = true;
        }
      }
      if (!fin){ j -= nb; if (j < 0) fin = true; }
    }
    excl = running;
    st_st(&status[vt*256u + d], (epoch << 29) | (2u << 27) | (excl + cnt));
  }
  gput[d] = dbase + excl - ldig;
  wrun[d]       = ldig;
  wrun[256 + d] = ldig + c0;
  wrun[512 + d] = ldig + c0 + c1;
  wrun[768 + d] = ldig + c0 + c1 + c2;
  __syncthreads();
  #pragma unroll
  for (int r = 0; r < 16; r++)
    stage[ wrun[w*256 + dg[r]] + rnk[r] ] = elems[r];
  __syncthreads();
  #pragma unroll
  for (int r = 0; r < 16; r++){
    unsigned jj = (unsigned)r * 256u + t;
    uint64_t e = stage[jj];
    unsigned dd = (unsigned)((e >> shift) & 0xFF);
    unsigned dest = gput[dd] + jj;
    if (FINAL){
      if (dest < R_N){
        uint32_t key = (uint32_t)(e >> 32);
        fout[2u*dest]        = (float)(key >> 12);
        fout[2u*dest + 1u]   = (float)(key & 4095u);
        fout[2u*R_N + dest]  = __uint_as_float(~(uint32_t)e);
      }
    } else {
      out[dest] = e;
    }
  }
}

__global__ __launch_bounds__(256) void k_scat(const uint64_t* __restrict__ in,
                                              uint64_t* __restrict__ out,
                                              unsigned shift, unsigned epoch,
                                              unsigned* __restrict__ status,
                                              const unsigned* __restrict__ drow,
                                              unsigned* __restrict__ ticket){
  scatter_os<false>(in, out, nullptr, shift, epoch, status, drow, ticket);
}

__global__ __launch_bounds__(256) void k_scat_out(const uint64_t* __restrict__ in,
                                                  float* __restrict__ fout,
                                                  unsigned shift, unsigned epoch,
                                                  unsigned* __restrict__ status,
                                                  const unsigned* __restrict__ drow,
                                                  unsigned* __restrict__ ticket){
  scatter_os<true>(in, nullptr, fout, shift, epoch, status, drow, ticket);
}

// Count real segment heads per 256-elem block (pad heads excluded -> total = U).
__global__ __launch_bounds__(256) void k_headcount(const uint64_t* __restrict__ in,
                                                   unsigned* __restrict__ hcnt){
  __shared__ unsigned wc[4];
  unsigned t = threadIdx.x, lane = t & 63u, w = t >> 6;
  size_t p = (size_t)blockIdx.x * 256 + t;
  uint64_t e = in[p];
  uint32_t k = (uint32_t)(e >> 32);
  bool head = ((p == 0) || ((uint32_t)(in[p-1] >> 32) != k)) && ((uint32_t)e != PAD_VAL);
  uint64_t m = __ballot(head);
  if (lane == 0) wc[w] = (unsigned)__popcll(m);
  __syncthreads();
  if (t == 0) hcnt[blockIdx.x] = wc[0] + wc[1] + wc[2] + wc[3];
}

// Fast single-block scan of NSB head counts via u16 LDS staging; writes U.
__global__ __launch_bounds__(256) void k_scanheads(unsigned* __restrict__ hcnt,
                                                   unsigned* __restrict__ utot){
  __shared__ unsigned short buf[NSB];    // 34.4 KB
  __shared__ unsigned lw[4];
  unsigned t = threadIdx.x;
  for (unsigned i = t; i < NSB; i += 256) buf[i] = (unsigned short)hcnt[i];
  __syncthreads();
  const unsigned CH = (NSB + 255) / 256;
  unsigned s = 0;
  for (unsigned k = 0; k < CH; k++){
    unsigned i = t * CH + k;
    if (i < NSB) s += buf[i];
  }
  unsigned tot;
  unsigned carry = blockScanExcl(s, t, lw, &tot);
  for (unsigned k = 0; k < CH; k++){
    unsigned i = t * CH + k;
    if (i < NSB){ unsigned v = buf[i]; hcnt[i] = carry; carry += v; }
  }
  if (t == 0) utot[0] = tot;
}

// Sentinel-fill only [U, NPAD).
__global__ __launch_bounds__(256) void k_fill_tail(uint64_t* __restrict__ A,
                                                   const unsigned* __restrict__ utot){
  unsigned U = utot[0];
  unsigned i = blockIdx.x * 256u + threadIdx.x;
  if (i >= U) A[i] = ((uint64_t)PAD_KEY << 32) | (uint64_t)PAD_VAL;
}

// In-order segmented sum (fp32, original contribution order -> bit-identical
// to segment_sum). Candidates written dense, key-ascending.
__global__ __launch_bounds__(256) void k_segsum(const uint64_t* __restrict__ in,
                                                uint64_t* __restrict__ out,
                                                const unsigned* __restrict__ hbase){
  __shared__ unsigned wc[4], woffs[4];
  unsigned t = threadIdx.x, lane = t & 63u, w = t >> 6;
  size_t p = (size_t)blockIdx.x * 256 + t;
  uint64_t e0 = in[p];
  uint32_t k = (uint32_t)(e0 >> 32);
  bool head = ((p == 0) || ((uint32_t)(in[p-1] >> 32) != k)) && ((uint32_t)e0 != PAD_VAL);
  uint64_t m = __ballot(head);
  if (lane == 0) wc[w] = (unsigned)__popcll(m);
  __syncthreads();
  if (t == 0){ unsigned a = 0; for (int i = 0; i < 4; i++){ woffs[i] = a; a += wc[i]; } }
  __syncthreads();
  if (head){
    uint64_t ltm = (lane == 0) ? 0ull : (~0ull >> (64u - lane));
    unsigned rank = (unsigned)__popcll(m & ltm);
    unsigned oidx = hbase[blockIdx.x] + woffs[w] + rank;
    float s = __uint_as_float((uint32_t)e0);
    size_t q = p + 1;
    while (q < NPAD){
      uint64_t e = in[q];
      if ((uint32_t)(e >> 32) != k) break;
      uint32_t vb = (uint32_t)e;
      if (vb == PAD_VAL) break;
      s += __uint_as_float(vb);
      q++;
    }
    out[oidx] = ((uint64_t)k << 32) | (uint64_t)(uint32_t)(~__float_as_uint(s));
  }
}

extern "C" void kernel_launch(void* const* d_in, const int* in_sizes, int n_in,
                              void* d_out, int out_size, void* d_ws, size_t ws_size,
                              hipStream_t stream) {
  const int*   sidx = (const int*)d_in[0];
  const int*   ridx = (const int*)d_in[1];
  const float* rval = (const float*)d_in[2];
  const float* grad = (const float*)d_in[3];
  float* out = (float*)d_out;

  uint64_t* A0      = (uint64_t*)d_ws;                    // 35.3 MB
  uint64_t* A1      = A0 + NPAD;                          // 35.3 MB
  unsigned* status  = (unsigned*)(A1 + NPAD);             // NTILES*256 u32 = 1.10 MB
  unsigned* dtotAll = status + NTILES*256;                // 7*256 u32
  unsigned* tickets = dtotAll + 7*256;                    // 8 u32
  unsigned* hcnt    = tickets + 8;                        // NSB u32 = 67 KB
  unsigned* utot    = hcnt + NSB;                         // 1 u32

  const unsigned NZ = NTILES*256 + 7*256 + 8;             // status + dtotAll + tickets
  k_zero<<<(NZ + 255)/256, 256, 0, stream>>>(status, NZ);

  k_build_h3<<<NTILES, 256, 0, stream>>>(sidx, ridx, rval, grad, A0, dtotAll);

  // Stable key sort: 3 x 8-bit onesweep passes. A0->A1->A0->A1.
  k_scat<<<NTILES, 256, 0, stream>>>(A0, A1, 32, 1, status, dtotAll + 0*256, tickets + 0);
  k_scat<<<NTILES, 256, 0, stream>>>(A1, A0, 40, 2, status, dtotAll + 1*256, tickets + 1);
  k_scat<<<NTILES, 256, 0, stream>>>(A0, A1, 48, 3, status, dtotAll + 2*256, tickets + 2);

  // Coalesce.
  k_headcount<<<NSB, 256, 0, stream>>>(A1, hcnt);
  k_scanheads<<<1,   256, 0, stream>>>(hcnt, utot);
  k_fill_tail<<<NSB, 256, 0, stream>>>(A0, utot);
  k_segsum   <<<NSB, 256, 0, stream>>>(A1, A0, hcnt);

  // Value-digit global histograms (one pass), then 4 onesweep passes with the
  // final pass fused with output emission. A0->A1->A0->A1->out.
  k_ghist4<<<NTILES, 256, 0, stream>>>(A0, dtotAll);
  k_scat    <<<NTILES, 256, 0, stream>>>(A0, A1,  0, 4, status, dtotAll + 3*256, tickets + 3);
  k_scat    <<<NTILES, 256, 0, stream>>>(A1, A0,  8, 5, status, dtotAll + 4*256, tickets + 4);
  k_scat    <<<NTILES, 256, 0, stream>>>(A0, A1, 16, 6, status, dtotAll + 5*256, tickets + 5);
  k_scat_out<<<NTILES, 256, 0, stream>>>(A1, out, 24, 7, status, dtotAll + 6*256, tickets + 6);
}